// Round 9
// baseline (760.288 us; speedup 1.0000x reference)
//
#include <hip/hip_runtime.h>
#include <hip/hip_bf16.h>

typedef unsigned short u16;
typedef unsigned int u32;
typedef __attribute__((ext_vector_type(8))) short short8;
typedef __attribute__((ext_vector_type(4))) float f32x4;
typedef __attribute__((ext_vector_type(2))) float f32x2;

#define HD 128

__device__ inline float b2f(u16 u){ u32 v = ((u32)u) << 16; return __uint_as_float(v); }
__device__ inline u16 f2b(float f){
  u32 u = __float_as_uint(f);
  u32 r = (u + 0x7fffu + ((u >> 16) & 1u)) >> 16;
  return (u16)r;
}
// packed f32x2 -> bf16x2 via HW convert
__device__ inline u32 pack2(float a, float b){
  __hip_bfloat162 h = __float22bfloat162_rn(make_float2(a, b));
  union { __hip_bfloat162 h; u32 u; } c; c.h = h; return c.u;
}
__device__ inline float lo2f(u32 w){ return b2f((u16)(w & 0xffff)); }
__device__ inline float hi2f(u32 w){ return b2f((u16)(w >> 16)); }
__device__ inline float eluf(float x){ return x > 0.f ? x : __expf(x) - 1.f; }
__device__ inline float reluf(float x){ return x > 0.f ? x : 0.f; }
__device__ inline float sane(float x){
  if (!(x == x)) return 0.f;
  return fminf(fmaxf(x, -1e30f), 1e30f);
}
// monotone float<->u32 encoding for atomicMax on signed floats
__device__ inline u32 fenc(float f){ u32 u = __float_as_uint(f); return (u & 0x80000000u) ? ~u : (u | 0x80000000u); }
__device__ inline float fdec(u32 u){ return __uint_as_float((u & 0x80000000u) ? (u & 0x7fffffffu) : ~u); }
// async 16B global->LDS
__device__ __forceinline__ void async16(const u16* g, u16* l){
  __builtin_amdgcn_global_load_lds((const __attribute__((address_space(1))) void*)g,
                                   (__attribute__((address_space(3))) void*)l, 16, 0, 0);
}

// ---------------- small precompute ----------------
__global__ void k_small(const float* __restrict__ na_a, const float* __restrict__ sc_a,
                        const float* __restrict__ la_a, const float* __restrict__ gatW,
                        const float* __restrict__ gat_as, const float* __restrict__ gat_ad,
                        const float* __restrict__ gin_eps, float* __restrict__ sm,
                        u32* __restrict__ maxs)
{
  int t = threadIdx.x;
  if (t < 3) maxs[t] = 0u;
  if (t == 0){
    for (int l = 0; l < 3; l++){
      float a[4]; float mx = -1e30f;
      for (int i = 0; i < 4; i++){ a[i] = na_a[l*4+i]; mx = fmaxf(mx, a[i]); }
      float ssum = 0.f;
      for (int i = 0; i < 4; i++){ a[i] = __expf(a[i]-mx); ssum += a[i]; }
      for (int i = 0; i < 4; i++) sm[l*4+i] = a[i]/ssum;
    }
    for (int r = 0; r < 2; r++){
      float a0 = sc_a[r*2], a1 = sc_a[r*2+1];
      float mx = fmaxf(a0,a1);
      float e0 = __expf(a0-mx), e1 = __expf(a1-mx);
      sm[12+r] = e1/(e0+e1);
    }
    {
      float a0=la_a[0], a1=la_a[1], a2=la_a[2];
      float mx = fmaxf(fmaxf(a0,a1),a2);
      float e0=__expf(a0-mx), e1=__expf(a1-mx), e2=__expf(a2-mx);
      float ssum = e0+e1+e2;
      sm[14]=e0/ssum; sm[15]=e1/ssum; sm[16]=e2/ssum;
    }
    for (int l=0;l<3;l++) sm[17+l] = 1.f + gin_eps[l];
  }
  if (t < 128){
    for (int l=0;l<3;l++){
      float a1=0.f, a2=0.f;
      for (int k=0;k<128;k++){
        float wv = gatW[l*16384 + k*128 + t];
        a1 = fmaf(wv, gat_as[l*128+k], a1);
        a2 = fmaf(wv, gat_ad[l*128+k], a2);
      }
      sm[32  + l*128 + t] = a1;
      sm[416 + l*128 + t] = a2;
    }
  }
}

// -------- weight pre-conversion f32 -> bf16, PRE-SWIZZLED chunk order -------
__device__ __forceinline__ uint4 cvt8(const float* __restrict__ p){
  float4 v0 = *(const float4*)p;
  float4 v1 = *(const float4*)(p + 4);
  uint4 o;
  o.x = pack2(v0.x, v0.y);
  o.y = pack2(v0.z, v0.w);
  o.z = pack2(v1.x, v1.y);
  o.w = pack2(v1.z, v1.w);
  return o;
}
__global__ void k_wcvt(const float* __restrict__ lin1W, const float* __restrict__ gcnW,
                       const float* __restrict__ Ws, const float* __restrict__ Wn,
                       const float* __restrict__ ginW, const float* __restrict__ gatW,
                       u16* __restrict__ wsb)
{
  int i = blockIdx.x*256 + threadIdx.x;
  if (i >= 32768) return;
  int m = i >> 11;
  int j = i & 2047;
  int r = j >> 4, c = j & 15;
  const float* src;
  if (m == 0)       src = lin1W;
  else if (m < 4)   src = gcnW + (m-1)*16384;
  else if (m < 7)   src = Ws   + (m-4)*16384;
  else if (m < 10)  src = Wn   + (m-7)*16384;
  else if (m < 13)  src = ginW + (m-10)*16384;
  else              src = gatW + (m-13)*16384;
  int dj = r*16 + (c ^ (r & 15));
  *(uint4*)(wsb + ((size_t)m*2048 + dj)*8) = cvt8(src + r*HD + c*8);
}

// ---------------- CSR build (multi-block scan + bucketed fill) --------------
__global__ void k_count(const int* __restrict__ ei, int E, int* __restrict__ cnt){
  int e = blockIdx.x*256 + threadIdx.x;
  if (e < E) atomicAdd(&cnt[ei[E + e]], 1);
}

__global__ void k_scan1(const int* __restrict__ cnt, int Nn, int* __restrict__ bsum){
  __shared__ int red[256];
  int b = blockIdx.x, t = threadIdx.x;
  int base = b*1024 + t*4;
  int s = 0;
  #pragma unroll
  for (int k = 0; k < 4; k++){ int i = base + k; if (i < Nn) s += cnt[i]; }
  red[t] = s; __syncthreads();
  for (int off = 128; off; off >>= 1){
    if (t < off) red[t] += red[t + off];
    __syncthreads();
  }
  if (t == 0) bsum[b] = red[0];
}

__global__ void k_scan2(const int* __restrict__ bsum, int nb,
                        int* __restrict__ boffs, int* __restrict__ rowptr, int Nn){
  __shared__ int sc[1024];
  int t = threadIdx.x;
  int own = (t < nb) ? bsum[t] : 0;
  sc[t] = own;
  __syncthreads();
  for (int off = 1; off < 1024; off <<= 1){
    int add = (t >= off) ? sc[t - off] : 0;
    __syncthreads();
    sc[t] += add;
    __syncthreads();
  }
  if (t < nb) boffs[t] = sc[t] - own;
  if (t == 1023) rowptr[Nn] = sc[1023];
}

__global__ void k_scan3(const int* __restrict__ cnt, const int* __restrict__ boffs, int Nn,
                        int* __restrict__ rowptr, float4* __restrict__ nd){
  __shared__ int red[256];
  int b = blockIdx.x, t = threadIdx.x;
  int base = b*1024 + t*4;
  int c[4]; int s = 0;
  #pragma unroll
  for (int k = 0; k < 4; k++){ int i = base + k; c[k] = (i < Nn) ? cnt[i] : 0; s += c[k]; }
  red[t] = s; __syncthreads();
  for (int off = 1; off < 256; off <<= 1){
    int add = (t >= off) ? red[t - off] : 0;
    __syncthreads();
    red[t] += add;
    __syncthreads();
  }
  int run = red[t] - s + boffs[b];
  #pragma unroll
  for (int k = 0; k < 4; k++){
    int i = base + k;
    if (i < Nn){
      rowptr[i] = run;
      float f = (float)c[k];
      nd[i].z = c[k] > 0 ? 1.f/sqrtf(f) : 0.f;   // dis
      nd[i].w = 1.f/fmaxf(f, 1.f);               // dinv
      run += c[k];
    }
  }
}

// bucket cursors: bucket b covers nodes [b*128, b*128+128)
__global__ void k_bcur(const int* __restrict__ rowptr, int nb2, int* __restrict__ bcur){
  for (int i = threadIdx.x; i < nb2; i += 512) bcur[i] = rowptr[i << 7];
}
// pass 1: append (src,dst) pairs into per-bucket regions (locality-friendly)
__global__ void k_bin(const int* __restrict__ ei, int E, int* __restrict__ bcur,
                      uint2* __restrict__ bp){
  int e = blockIdx.x*256 + threadIdx.x;
  if (e < E){
    int sv = ei[e], dv = ei[E + e];
    int pos = atomicAdd(&bcur[dv >> 7], 1);
    bp[pos] = make_uint2((u32)sv, (u32)dv);
  }
}
// pass 2: per-bucket LDS-cursor fill; csr writes land in an 8 KB L2 window
__global__ __launch_bounds__(256)
void k_fill2(const uint2* __restrict__ bp, const int* __restrict__ rowptr, int Nn,
             int* __restrict__ csr){
  __shared__ int lcur[128];
  int b = blockIdx.x, t = threadIdx.x;
  int nb0 = b << 7;
  int nend = min(nb0 + 128, Nn);
  if (t < 128 && nb0 + t < nend) lcur[t] = rowptr[nb0 + t];
  __syncthreads();
  int ebeg = rowptr[nb0], eend = rowptr[nend];
  for (int e = ebeg + t; e < eend; e += 256){
    uint2 pr = bp[e];
    int pos = atomicAdd(&lcur[pr.y & 127], 1);
    csr[pos] = (int)pr.x;
  }
}

// ------- aggregation: wave/dst, single pass (global softmax bound) ----------
__global__ __launch_bounds__(256)
void k_agg(const u16* __restrict__ X, const int* __restrict__ rowptr, const int* __restrict__ csr,
           const float4* __restrict__ nd, const float* __restrict__ sm,
           const u32* __restrict__ maxs, int layer, int Nn,
           u16* __restrict__ Qb, u16* __restrict__ Pm, u16* __restrict__ Gb, u16* __restrict__ Rb,
           float* __restrict__ b0)
{
  int wv = blockIdx.x*4 + (threadIdx.x >> 6);
  if (wv >= Nn) return;
  int lane = threadIdx.x & 63;
  int g = lane >> 4, t = lane & 15;
  int beg = rowptr[wv], end = rowptr[wv+1];
  float4 ndw = nd[wv];
  float dval = ndw.y;
  float bnd = fdec(maxs[layer]) + dval;
  float mloc = fmaxf(bnd, 0.2f*bnd);
  f32x2 p2[4], q2[4], r2[4];
  #pragma unroll
  for (int k = 0; k < 4; k++){ p2[k] = (f32x2){0.f,0.f}; q2[k] = (f32x2){0.f,0.f}; r2[k] = (f32x2){0.f,0.f}; }
  float z = 0.f, qd = 0.f;
  int e = beg + g;
  for (; e + 4 < end; e += 8){
    int sv0 = csr[e], sv1 = csr[e+4];
    float4 n0 = nd[sv0], n1 = nd[sv1];
    uint4 xv0 = *(const uint4*)(X + (size_t)sv0*HD + (t ^ (sv0 & 15))*8);
    uint4 xv1 = *(const uint4*)(X + (size_t)sv1*HD + (t ^ (sv1 & 15))*8);
    float s0 = n0.x + dval, s1 = n1.x + dval;
    float lg0 = fmaxf(s0, 0.2f*s0);
    float lg1 = fmaxf(s1, 0.2f*s1);
    float ew0 = __expf(lg0 - mloc), ew1 = __expf(lg1 - mloc);
    u32 a0[4] = {xv0.x, xv0.y, xv0.z, xv0.w};
    u32 a1[4] = {xv1.x, xv1.y, xv1.z, xv1.w};
    f32x2 d0 = {n0.z, n0.z}, d1 = {n1.z, n1.z};
    f32x2 e0 = {ew0, ew0},   e1v = {ew1, ew1};
    #pragma unroll
    for (int k = 0; k < 4; k++){
      f32x2 xf0 = {lo2f(a0[k]), hi2f(a0[k])};
      f32x2 xf1 = {lo2f(a1[k]), hi2f(a1[k])};
      p2[k] += xf0 + xf1;
      q2[k] = __builtin_elementwise_fma(xf0, d0, q2[k]);
      q2[k] = __builtin_elementwise_fma(xf1, d1, q2[k]);
      r2[k] = __builtin_elementwise_fma(xf0, e0, r2[k]);
      r2[k] = __builtin_elementwise_fma(xf1, e1v, r2[k]);
    }
    z += ew0 + ew1; qd += n0.z + n1.z;
  }
  if (e < end){
    int sv = csr[e];
    float4 n0 = nd[sv];
    uint4 xv = *(const uint4*)(X + (size_t)sv*HD + (t ^ (sv & 15))*8);
    float s = n0.x + dval;
    float lg = fmaxf(s, 0.2f*s);
    float ew = __expf(lg - mloc);
    u32 a0[4] = {xv.x, xv.y, xv.z, xv.w};
    f32x2 d0 = {n0.z, n0.z}, e0 = {ew, ew};
    #pragma unroll
    for (int k = 0; k < 4; k++){
      f32x2 xf = {lo2f(a0[k]), hi2f(a0[k])};
      p2[k] += xf;
      q2[k] = __builtin_elementwise_fma(xf, d0, q2[k]);
      r2[k] = __builtin_elementwise_fma(xf, e0, r2[k]);
    }
    z += ew; qd += n0.z;
  }
  #pragma unroll
  for (int off = 16; off <= 32; off <<= 1){
    #pragma unroll
    for (int k = 0; k < 4; k++){
      p2[k].x += __shfl_xor(p2[k].x, off); p2[k].y += __shfl_xor(p2[k].y, off);
      q2[k].x += __shfl_xor(q2[k].x, off); q2[k].y += __shfl_xor(q2[k].y, off);
      r2[k].x += __shfl_xor(r2[k].x, off); r2[k].y += __shfl_xor(r2[k].y, off);
    }
    z  += __shfl_xor(z, off);
    qd += __shfl_xor(qd, off);
  }
  if (g == 0){
    float disv = ndw.z, dinvv = ndw.w;
    float zinv = 1.f/(z + 1e-16f);
    float e1 = sm[17 + layer];
    int tch = t ^ (wv & 15);
    size_t o = (size_t)wv*HD + tch*8;
    uint4 xo = *(const uint4*)(X + o);
    u32 ax[4] = {xo.x, xo.y, xo.z, xo.w};
    uint4 qo, po, go, ro;
    u32* qp = (u32*)&qo; u32* pp = (u32*)&po; u32* gp = (u32*)&go; u32* rp = (u32*)&ro;
    #pragma unroll
    for (int k = 0; k < 4; k++){
      float x0 = lo2f(ax[k]), x1 = hi2f(ax[k]);
      qp[k] = pack2(disv*q2[k].x, disv*q2[k].y);
      pp[k] = pack2(dinvv*p2[k].x, dinvv*p2[k].y);
      gp[k] = pack2(fmaf(e1, x0, p2[k].x), fmaf(e1, x1, p2[k].y));
      rp[k] = pack2(zinv*r2[k].x, zinv*r2[k].y);
    }
    *(uint4*)(Qb + o) = qo;
    *(uint4*)(Pm + o) = po;
    *(uint4*)(Gb + o) = go;
    *(uint4*)(Rb + o) = ro;
    if (t == 0) b0[wv] = disv*qd;
  }
}

// ---------------- MFMA helpers, M=64 tile ----------------
__device__ __forceinline__ void stageB_async(u16* lds, const u16* __restrict__ w, int tid){
  int lane = tid & 63, wave = tid >> 6;
  #pragma unroll
  for (int i = 0; i < 8; i++){
    int cb = wave*64 + 256*i;
    async16(w + (size_t)(cb + lane)*8, lds + (size_t)cb*8);
  }
}
__device__ __forceinline__ void stageA64_async(u16* lds, const u16* __restrict__ src,
                                               int mbase, int Nn, int tid){
  int lane = tid & 63, wave = tid >> 6;
  #pragma unroll
  for (int i = 0; i < 4; i++){
    int cb = wave*64 + 256*i;
    int gr = mbase + ((cb + lane) >> 4);
    if (gr < Nn)
      async16(src + ((size_t)mbase*16 + cb + lane)*8, lds + (size_t)cb*8);
  }
}
__device__ __forceinline__ void stageA64_f32(u16* lds, const float* __restrict__ src,
                                             int mbase, int Nn, int tid){
  #pragma unroll
  for (int i = 0; i < 4; i++){
    int chunk = tid + 256*i;
    int r = chunk >> 4;
    int c = chunk & 15;
    uint4 v = {0u,0u,0u,0u};
    int gr = mbase + r;
    if (gr < Nn) v = cvt8(src + (size_t)gr*HD + c*8);
    *(uint4*)(lds + (r*16 + (c ^ (r & 15)))*8) = v;
  }
}
__device__ __forceinline__ void mfma_tile64(const u16* Als, const u16* Bls,
                                            int m0, int lane, f32x4 acc[8]){
  int quad = lane >> 4, lr = lane & 15;
  #pragma unroll
  for (int ks = 0; ks < 4; ks++){
    int q = ks*4 + quad;
    short8 a, b[8];
    int row = m0 + lr;
    a = *(const short8*)(Als + (row*16 + (q ^ lr))*8);
    #pragma unroll
    for (int ct = 0; ct < 8; ct++){
      int brow = ct*16 + lr;
      b[ct] = *(const short8*)(Bls + (brow*16 + (q ^ lr))*8);
    }
    #pragma unroll
    for (int ct = 0; ct < 8; ct++)
      acc[ct] = __builtin_amdgcn_mfma_f32_16x16x32_bf16(a, b[ct], acc[ct], 0, 0, 0);
  }
}

// ---------------- lin1: xh(bf16,swz) = f32(x) @ W^T + b ----------------
__global__ __launch_bounds__(256,3)
void k_gemm1(const float* __restrict__ A, const u16* __restrict__ Wb, const float* __restrict__ bias,
             const float* __restrict__ sm, float4* __restrict__ nd, u32* __restrict__ maxs,
             int Nn, u16* __restrict__ out)
{
  __shared__ __align__(16) u16 Als[64*128];
  __shared__ __align__(16) u16 Bls[128*128];
  __shared__ float mred[4];
  int tid = threadIdx.x;
  int lane = tid & 63, wave = tid >> 6;
  int m0 = wave*16, mbase = blockIdx.x*64;
  int quad = lane >> 4, lr = lane & 15;
  f32x4 acc[8];
  #pragma unroll
  for (int ct=0;ct<8;ct++) acc[ct] = (f32x4){0.f,0.f,0.f,0.f};
  stageB_async(Bls, Wb, tid);
  stageA64_f32(Als, A, mbase, Nn, tid);
  __syncthreads();
  mfma_tile64(Als, Bls, m0, lane, acc);
  #pragma unroll
  for (int ct=0;ct<8;ct++){
    float bc = bias[ct*16+lr];
    #pragma unroll
    for (int r=0;r<4;r++) acc[ct][r] = sane(acc[ct][r] + bc);
  }
  #pragma unroll
  for (int ct=0;ct<8;ct++){
    int c2 = ct*2 + (lr >> 3);
    #pragma unroll
    for (int r=0;r<4;r++){
      int grow = mbase + m0 + quad*4 + r;
      if (grow < Nn) out[(size_t)grow*HD + (c2 ^ (grow & 15))*8 + (lr & 7)] = f2b(acc[ct][r]);
    }
  }
  {
    const float* wsv = sm + 32;
    const float* wdv = sm + 416;
    float sp[4] = {0.f,0.f,0.f,0.f}, dp[4] = {0.f,0.f,0.f,0.f};
    #pragma unroll
    for (int ct=0;ct<8;ct++){
      float wsc = wsv[ct*16+lr], wdc = wdv[ct*16+lr];
      #pragma unroll
      for (int r=0;r<4;r++){
        sp[r] = fmaf(acc[ct][r], wsc, sp[r]);
        dp[r] = fmaf(acc[ct][r], wdc, dp[r]);
      }
    }
    #pragma unroll
    for (int off=1; off<16; off<<=1)
      #pragma unroll
      for (int r=0;r<4;r++){ sp[r] += __shfl_xor(sp[r], off); dp[r] += __shfl_xor(dp[r], off); }
    float ms = -3.4e38f;
    #pragma unroll
    for (int r=0;r<4;r++){
      int grow = mbase + m0 + quad*4 + r;
      if (grow < Nn){
        ms = fmaxf(ms, sp[r]);
        if (lr == 0) *(float2*)&nd[grow] = make_float2(sp[r], dp[r]);
      }
    }
    ms = fmaxf(ms, __shfl_xor(ms, 16));
    ms = fmaxf(ms, __shfl_xor(ms, 32));
    if (lane == 0) mred[wave] = ms;
    __syncthreads();
    if (tid == 0){
      float m = fmaxf(fmaxf(mred[0],mred[1]), fmaxf(mred[2],mred[3]));
      atomicMax(maxs + 0, fenc(m));
    }
  }
}

// ---------------- fused layer: 5 all-async GEMMs + elu mix + s/d epilogue ---
__global__ __launch_bounds__(256,3)
void k_layer3(const u16* __restrict__ X, const u16* __restrict__ Qb,
              const u16* __restrict__ Pm, const u16* __restrict__ Gb, const u16* __restrict__ Rb,
              float4* __restrict__ nd, const float* __restrict__ b0,
              const u16* __restrict__ wsb,
              const float* __restrict__ gcnB, const float* __restrict__ ginB,
              const float* __restrict__ sm, u32* __restrict__ maxs,
              int layer, int Nn, u16* __restrict__ out)
{
  __shared__ __align__(16) u16 At[64*128];
  __shared__ __align__(16) u16 Bt[128*128];
  __shared__ float mred[4];
  int tid = threadIdx.x;
  int lane = tid & 63, wave = tid >> 6;
  int m0 = wave*16, mbase = blockIdx.x*64;
  int quad = lane >> 4, lr = lane & 15;
  float w0 = sm[layer*4+0], w1 = sm[layer*4+1], w2 = sm[layer*4+2], w3 = sm[layer*4+3];
  const u16* gcnWb = wsb + (size_t)(1  + layer)*16384;
  const u16* WsWb  = wsb + (size_t)(4  + layer)*16384;
  const u16* WnWb  = wsb + (size_t)(7  + layer)*16384;
  const u16* ginWb = wsb + (size_t)(10 + layer)*16384;
  const u16* gatWb = wsb + (size_t)(13 + layer)*16384;

  f32x4 mix[8];
  f32x4 acc[8];
  float b0r[4];
  #pragma unroll
  for (int r=0;r<4;r++){
    int grow = mbase + m0 + quad*4 + r;
    b0r[r] = (grow < Nn) ? b0[grow] : 0.f;
  }

  // ---- op0: GCN ----
  stageB_async(Bt, gcnWb, tid);
  stageA64_async(At, Qb, mbase, Nn, tid);
  __syncthreads();
  #pragma unroll
  for (int ct=0;ct<8;ct++) acc[ct] = (f32x4){0.f,0.f,0.f,0.f};
  mfma_tile64(At, Bt, m0, lane, acc);
  {
    float gb[8];
    #pragma unroll
    for (int ct=0;ct<8;ct++) gb[ct] = gcnB[layer*HD + ct*16+lr];
    #pragma unroll
    for (int ct=0;ct<8;ct++)
      #pragma unroll
      for (int r=0;r<4;r++)
        mix[ct][r] = w0 * eluf(acc[ct][r] + b0r[r]*gb[ct]);
  }
  __syncthreads();

  // ---- op1: SAGE self ----
  stageB_async(Bt, WsWb, tid);
  stageA64_async(At, X, mbase, Nn, tid);
  __syncthreads();
  #pragma unroll
  for (int ct=0;ct<8;ct++) acc[ct] = (f32x4){0.f,0.f,0.f,0.f};
  mfma_tile64(At, Bt, m0, lane, acc);
  __syncthreads();
  // ---- SAGE neighbor ----
  stageB_async(Bt, WnWb, tid);
  stageA64_async(At, Pm, mbase, Nn, tid);
  __syncthreads();
  mfma_tile64(At, Bt, m0, lane, acc);
  #pragma unroll
  for (int ct=0;ct<8;ct++)
    #pragma unroll
    for (int r=0;r<4;r++)
      mix[ct][r] += w1 * eluf(acc[ct][r]);
  __syncthreads();

  // ---- op2: GIN ----
  stageB_async(Bt, ginWb, tid);
  stageA64_async(At, Gb, mbase, Nn, tid);
  __syncthreads();
  #pragma unroll
  for (int ct=0;ct<8;ct++) acc[ct] = (f32x4){0.f,0.f,0.f,0.f};
  mfma_tile64(At, Bt, m0, lane, acc);
  {
    float gib[8];
    #pragma unroll
    for (int ct=0;ct<8;ct++) gib[ct] = ginB[layer*HD + ct*16+lr];
    #pragma unroll
    for (int ct=0;ct<8;ct++)
      #pragma unroll
      for (int r=0;r<4;r++)
        mix[ct][r] += w2 * eluf(acc[ct][r] + gib[ct]);
  }
  __syncthreads();

  // ---- op3: GAT ----
  stageB_async(Bt, gatWb, tid);
  stageA64_async(At, Rb, mbase, Nn, tid);
  __syncthreads();
  #pragma unroll
  for (int ct=0;ct<8;ct++) acc[ct] = (f32x4){0.f,0.f,0.f,0.f};
  mfma_tile64(At, Bt, m0, lane, acc);
  #pragma unroll
  for (int ct=0;ct<8;ct++)
    #pragma unroll
    for (int r=0;r<4;r++)
      mix[ct][r] = sane(mix[ct][r] + w3 * eluf(acc[ct][r]));

  // ---- store swizzled ----
  #pragma unroll
  for (int ct=0;ct<8;ct++){
    int c2 = ct*2 + (lr >> 3);
    #pragma unroll
    for (int r=0;r<4;r++){
      int grow = mbase + m0 + quad*4 + r;
      if (grow < Nn) out[(size_t)grow*HD + (c2 ^ (grow & 15))*8 + (lr & 7)] = f2b(mix[ct][r]);
    }
  }
  // ---- epilogue: s,d for next layer + global maxS ----
  if (layer < 2){
    const float* wsv = sm + 32  + (layer+1)*128;
    const float* wdv = sm + 416 + (layer+1)*128;
    float sp[4] = {0.f,0.f,0.f,0.f}, dp[4] = {0.f,0.f,0.f,0.f};
    #pragma unroll
    for (int ct=0;ct<8;ct++){
      float wsc = wsv[ct*16+lr], wdc = wdv[ct*16+lr];
      #pragma unroll
      for (int r=0;r<4;r++){
        sp[r] = fmaf(mix[ct][r], wsc, sp[r]);
        dp[r] = fmaf(mix[ct][r], wdc, dp[r]);
      }
    }
    #pragma unroll
    for (int off=1; off<16; off<<=1)
      #pragma unroll
      for (int r=0;r<4;r++){ sp[r] += __shfl_xor(sp[r], off); dp[r] += __shfl_xor(dp[r], off); }
    float ms = -3.4e38f;
    #pragma unroll
    for (int r=0;r<4;r++){
      int grow = mbase + m0 + quad*4 + r;
      if (grow < Nn){
        ms = fmaxf(ms, sp[r]);
        if (lr == 0) *(float2*)&nd[grow] = make_float2(sp[r], dp[r]);
      }
    }
    ms = fmaxf(ms, __shfl_xor(ms, 16));
    ms = fmaxf(ms, __shfl_xor(ms, 32));
    if (lane == 0) mred[wave] = ms;
    __syncthreads();
    if (tid == 0){
      float m = fmaxf(fmaxf(mred[0],mred[1]), fmaxf(mred[2],mred[3]));
      atomicMax(maxs + layer + 1, fenc(m));
    }
  }
}

// ------- classifier with fused skip/layer-agg (inputs swizzled) ----------
__global__ __launch_bounds__(256)
void k_nc(const u16* __restrict__ X1, const u16* __restrict__ X2, const u16* __restrict__ X3,
          const float* __restrict__ W, const float* __restrict__ bias,
          const float* __restrict__ sm, int Nn, float* __restrict__ out)
{
  __shared__ __align__(16) u16 xs[32*136];
  __shared__ __align__(16) float wn[40*132];
  __shared__ float bs[40];
  int t = threadIdx.x;
  int nb = blockIdx.x*32;
  float c1 = sm[12], c2 = sm[13], la0 = sm[14], la1 = sm[15], la2 = sm[16];
  #pragma unroll
  for (int i = 0; i < 2; i++){
    int chunk = t + 256*i;
    int r = chunk >> 4, c = chunk & 15;
    uint4 v = {0u,0u,0u,0u};
    int gr = nb + r;
    if (gr < Nn){
      size_t o = (size_t)gr*HD + ((c ^ (gr & 15))*8);
      uint4 u1 = *(const uint4*)(X1 + o);
      uint4 u2 = *(const uint4*)(X2 + o);
      uint4 u3 = *(const uint4*)(X3 + o);
      u32* u1p = (u32*)&u1; u32* u2p = (u32*)&u2; u32* u3p = (u32*)&u3; u32* vp = (u32*)&v;
      #pragma unroll
      for (int k = 0; k < 4; k++){
        float o0, o1;
        {
          float a1 = lo2f(u1p[k]), a2 = lo2f(u2p[k]), a3 = lo2f(u3p[k]);
          float t0 = a3, t1 = c1*a1, t2 = c2*a2;
          float smm = t0 + t1 + t2;
          float mx = fmaxf(fmaxf(t0,t1),t2);
          o0 = la0*reluf(mx) + la1*reluf(smm*(1.f/3.f)) + la2*reluf(smm);
        }
        {
          float a1 = hi2f(u1p[k]), a2 = hi2f(u2p[k]), a3 = hi2f(u3p[k]);
          float t0 = a3, t1 = c1*a1, t2 = c2*a2;
          float smm = t0 + t1 + t2;
          float mx = fmaxf(fmaxf(t0,t1),t2);
          o1 = la0*reluf(mx) + la1*reluf(smm*(1.f/3.f)) + la2*reluf(smm);
        }
        vp[k] = pack2(sane(o0), sane(o1));
      }
    }
    *(uint4*)(xs + r*136 + c*8) = v;
  }
  #pragma unroll
  for (int i = 0; i < 5; i++){
    int chunk = t + 256*i;
    int r = chunk >> 5, c = chunk & 31;
    *(float4*)(wn + r*132 + c*4) = *(const float4*)(W + r*HD + c*4);
  }
  if (t < 40) bs[t] = bias[t];
  __syncthreads();
  int nl = t >> 3, cg = t & 7;
  float acc[5];
  #pragma unroll
  for (int j = 0; j < 5; j++) acc[j] = bs[cg + 8*j];
  for (int k = 0; k < 128; k++){
    float xv = b2f(xs[nl*136 + k]);
    #pragma unroll
    for (int j = 0; j < 5; j++)
      acc[j] = fmaf(xv, wn[(cg + 8*j)*132 + k], acc[j]);
  }
  int gr = nb + nl;
  if (gr < Nn){
    #pragma unroll
    for (int j = 0; j < 5; j++)
      out[(size_t)gr*40 + cg + 8*j] = sane(acc[j]);
  }
}

// ---------------- host ----------------
extern "C" void kernel_launch(void* const* d_in, const int* in_sizes, int n_in,
                              void* d_out, int out_size, void* d_ws, size_t ws_size,
                              hipStream_t stream)
{
  (void)n_in; (void)out_size; (void)ws_size;
  const int N = in_sizes[0] / HD;
  const int E = in_sizes[1] / 2;
  const float* x      = (const float*)d_in[0];
  const int*   ei     = (const int*)d_in[1];
  const float* na_a   = (const float*)d_in[2];
  const float* sc_a   = (const float*)d_in[3];
  const float* la_a   = (const float*)d_in[4];
  const float* lin1W  = (const float*)d_in[5];
  const float* lin1b  = (const float*)d_in[6];
  const float* gcnW   = (const float*)d_in[7];
  const float* gcnB   = (const float*)d_in[8];
  const float* sageWs = (const float*)d_in[9];
  const float* sageWn = (const float*)d_in[10];
  const float* ginW   = (const float*)d_in[11];
  const float* ginB   = (const float*)d_in[12];
  const float* ginE   = (const float*)d_in[13];
  const float* gatW   = (const float*)d_in[14];
  const float* gatAs  = (const float*)d_in[15];
  const float* gatAd  = (const float*)d_in[16];
  const float* ncW    = (const float*)d_in[17];
  const float* ncB    = (const float*)d_in[18];

  char* base = (char*)d_ws;
  size_t off = 0;
  auto alloc = [&](size_t b) -> void* {
    void* p = base + off;
    off += (b + 255) & ~(size_t)255;
    return p;
  };
  const int NB  = (N + 1023) / 1024;
  const int NB2 = (N + 127) / 128;     // fill buckets (128 nodes each)
  float*  smalls = (float*)alloc(4096);
  u32*    maxs   = (u32*)alloc(256);
  int*    cnt    = (int*)alloc((size_t)N*4);
  int*    rowptr = (int*)alloc(((size_t)N+1)*4);
  int*    bsum   = (int*)alloc(4096);
  int*    boffs  = (int*)alloc(4096);
  int*    bcur   = (int*)alloc((size_t)NB2*4);
  float4* nd     = (float4*)alloc((size_t)N*16);
  float*  b0     = (float*)alloc((size_t)N*4);
  int*    csr    = (int*)alloc((size_t)E*4);
  uint2*  bp     = (uint2*)alloc((size_t)E*8);
  u16*    wsb    = (u16*)alloc((size_t)16*16384*2);
  u16*    xh     = (u16*)alloc((size_t)N*HD*2);
  u16*    x1     = (u16*)alloc((size_t)N*HD*2);
  u16*    x2     = (u16*)alloc((size_t)N*HD*2);
  u16*    Qb     = (u16*)alloc((size_t)N*HD*2);
  u16*    Pm     = (u16*)alloc((size_t)N*HD*2);
  u16*    Gb     = (u16*)alloc((size_t)N*HD*2);
  u16*    Rb     = (u16*)alloc((size_t)N*HD*2);

  hipMemsetAsync(cnt, 0, (size_t)N*4, stream);
  k_small<<<1,128,0,stream>>>(na_a, sc_a, la_a, gatW, gatAs, gatAd, ginE, smalls, maxs);
  k_wcvt<<<128,256,0,stream>>>(lin1W, gcnW, sageWs, sageWn, ginW, gatW, wsb);
  int ebl = (E + 255)/256;
  k_count<<<ebl,256,0,stream>>>(ei, E, cnt);
  k_scan1<<<NB,256,0,stream>>>(cnt, N, bsum);
  k_scan2<<<1,1024,0,stream>>>(bsum, NB, boffs, rowptr, N);
  k_scan3<<<NB,256,0,stream>>>(cnt, boffs, N, rowptr, nd);
  k_bcur<<<1,512,0,stream>>>(rowptr, NB2, bcur);
  k_bin<<<ebl,256,0,stream>>>(ei, E, bcur, bp);
  k_fill2<<<NB2,256,0,stream>>>(bp, rowptr, N, csr);
  int gbl64 = (N + 63)/64;
  k_gemm1<<<gbl64,256,0,stream>>>(x, wsb, lin1b, smalls, nd, maxs, N, xh);
  const u16* xc = xh;
  u16* outs[3] = {x1, x2, xh};
  int wbl = (N + 3)/4;
  for (int l = 0; l < 3; l++){
    k_agg<<<wbl,256,0,stream>>>(xc, rowptr, csr, nd, smalls, maxs, l, N, Qb, Pm, Gb, Rb, b0);
    k_layer3<<<gbl64,256,0,stream>>>(xc, Qb, Pm, Gb, Rb, nd, b0, wsb,
                                     gcnB, ginB, smalls, maxs, l, N, outs[l]);
    xc = outs[l];
  }
  int ncbl = (N + 31)/32;
  k_nc<<<ncbl,256,0,stream>>>(x1, x2, xh, ncW, ncB, smalls, N, (float*)d_out);
}

// Round 10
// 512.769 us; speedup vs baseline: 1.4827x; 1.4827x over previous
//
#include <hip/hip_runtime.h>
#include <hip/hip_bf16.h>

typedef unsigned short u16;
typedef unsigned int u32;
typedef __attribute__((ext_vector_type(8))) short short8;
typedef __attribute__((ext_vector_type(4))) float f32x4;
typedef __attribute__((ext_vector_type(2))) float f32x2;

#define HD 128

__device__ inline float b2f(u16 u){ u32 v = ((u32)u) << 16; return __uint_as_float(v); }
__device__ inline u16 f2b(float f){
  u32 u = __float_as_uint(f);
  u32 r = (u + 0x7fffu + ((u >> 16) & 1u)) >> 16;
  return (u16)r;
}
// packed f32x2 -> bf16x2 via HW convert
__device__ inline u32 pack2(float a, float b){
  __hip_bfloat162 h = __float22bfloat162_rn(make_float2(a, b));
  union { __hip_bfloat162 h; u32 u; } c; c.h = h; return c.u;
}
__device__ inline float lo2f(u32 w){ return b2f((u16)(w & 0xffff)); }
__device__ inline float hi2f(u32 w){ return b2f((u16)(w >> 16)); }
__device__ inline float eluf(float x){ return x > 0.f ? x : __expf(x) - 1.f; }
__device__ inline float reluf(float x){ return x > 0.f ? x : 0.f; }
__device__ inline float sane(float x){
  if (!(x == x)) return 0.f;
  return fminf(fmaxf(x, -1e30f), 1e30f);
}
// monotone float<->u32 encoding for atomicMax on signed floats
__device__ inline u32 fenc(float f){ u32 u = __float_as_uint(f); return (u & 0x80000000u) ? ~u : (u | 0x80000000u); }
__device__ inline float fdec(u32 u){ return __uint_as_float((u & 0x80000000u) ? (u & 0x7fffffffu) : ~u); }
// async 16B global->LDS
__device__ __forceinline__ void async16(const u16* g, u16* l){
  __builtin_amdgcn_global_load_lds((const __attribute__((address_space(1))) void*)g,
                                   (__attribute__((address_space(3))) void*)l, 16, 0, 0);
}

// ---------------- small precompute ----------------
__global__ void k_small(const float* __restrict__ na_a, const float* __restrict__ sc_a,
                        const float* __restrict__ la_a, const float* __restrict__ gatW,
                        const float* __restrict__ gat_as, const float* __restrict__ gat_ad,
                        const float* __restrict__ gin_eps, float* __restrict__ sm,
                        u32* __restrict__ maxs)
{
  int t = threadIdx.x;
  if (t < 3) maxs[t] = 0u;
  if (t == 0){
    for (int l = 0; l < 3; l++){
      float a[4]; float mx = -1e30f;
      for (int i = 0; i < 4; i++){ a[i] = na_a[l*4+i]; mx = fmaxf(mx, a[i]); }
      float ssum = 0.f;
      for (int i = 0; i < 4; i++){ a[i] = __expf(a[i]-mx); ssum += a[i]; }
      for (int i = 0; i < 4; i++) sm[l*4+i] = a[i]/ssum;
    }
    for (int r = 0; r < 2; r++){
      float a0 = sc_a[r*2], a1 = sc_a[r*2+1];
      float mx = fmaxf(a0,a1);
      float e0 = __expf(a0-mx), e1 = __expf(a1-mx);
      sm[12+r] = e1/(e0+e1);
    }
    {
      float a0=la_a[0], a1=la_a[1], a2=la_a[2];
      float mx = fmaxf(fmaxf(a0,a1),a2);
      float e0=__expf(a0-mx), e1=__expf(a1-mx), e2=__expf(a2-mx);
      float ssum = e0+e1+e2;
      sm[14]=e0/ssum; sm[15]=e1/ssum; sm[16]=e2/ssum;
    }
    for (int l=0;l<3;l++) sm[17+l] = 1.f + gin_eps[l];
  }
  if (t < 128){
    for (int l=0;l<3;l++){
      float a1=0.f, a2=0.f;
      for (int k=0;k<128;k++){
        float wv = gatW[l*16384 + k*128 + t];
        a1 = fmaf(wv, gat_as[l*128+k], a1);
        a2 = fmaf(wv, gat_ad[l*128+k], a2);
      }
      sm[32  + l*128 + t] = a1;
      sm[416 + l*128 + t] = a2;
    }
  }
}

// -------- weight pre-conversion f32 -> bf16, PRE-SWIZZLED chunk order -------
__device__ __forceinline__ uint4 cvt8(const float* __restrict__ p){
  float4 v0 = *(const float4*)p;
  float4 v1 = *(const float4*)(p + 4);
  uint4 o;
  o.x = pack2(v0.x, v0.y);
  o.y = pack2(v0.z, v0.w);
  o.z = pack2(v1.x, v1.y);
  o.w = pack2(v1.z, v1.w);
  return o;
}
__global__ void k_wcvt(const float* __restrict__ lin1W, const float* __restrict__ gcnW,
                       const float* __restrict__ Ws, const float* __restrict__ Wn,
                       const float* __restrict__ ginW, const float* __restrict__ gatW,
                       u16* __restrict__ wsb)
{
  int i = blockIdx.x*256 + threadIdx.x;
  if (i >= 32768) return;
  int m = i >> 11;
  int j = i & 2047;
  int r = j >> 4, c = j & 15;
  const float* src;
  if (m == 0)       src = lin1W;
  else if (m < 4)   src = gcnW + (m-1)*16384;
  else if (m < 7)   src = Ws   + (m-4)*16384;
  else if (m < 10)  src = Wn   + (m-7)*16384;
  else if (m < 13)  src = ginW + (m-10)*16384;
  else              src = gatW + (m-13)*16384;
  int dj = r*16 + (c ^ (r & 15));
  *(uint4*)(wsb + ((size_t)m*2048 + dj)*8) = cvt8(src + r*HD + c*8);
}

// ---------------- CSR build (multi-block scan + per-node-cursor fill) -------
__global__ void k_count(const int* __restrict__ ei, int E, int* __restrict__ cnt){
  int e = blockIdx.x*256 + threadIdx.x;
  if (e < E) atomicAdd(&cnt[ei[E + e]], 1);
}

__global__ void k_scan1(const int* __restrict__ cnt, int Nn, int* __restrict__ bsum){
  __shared__ int red[256];
  int b = blockIdx.x, t = threadIdx.x;
  int base = b*1024 + t*4;
  int s = 0;
  #pragma unroll
  for (int k = 0; k < 4; k++){ int i = base + k; if (i < Nn) s += cnt[i]; }
  red[t] = s; __syncthreads();
  for (int off = 128; off; off >>= 1){
    if (t < off) red[t] += red[t + off];
    __syncthreads();
  }
  if (t == 0) bsum[b] = red[0];
}

__global__ void k_scan2(const int* __restrict__ bsum, int nb,
                        int* __restrict__ boffs, int* __restrict__ rowptr, int Nn){
  __shared__ int sc[1024];
  int t = threadIdx.x;
  int own = (t < nb) ? bsum[t] : 0;
  sc[t] = own;
  __syncthreads();
  for (int off = 1; off < 1024; off <<= 1){
    int add = (t >= off) ? sc[t - off] : 0;
    __syncthreads();
    sc[t] += add;
    __syncthreads();
  }
  if (t < nb) boffs[t] = sc[t] - own;
  if (t == 1023) rowptr[Nn] = sc[1023];
}

__global__ void k_scan3(const int* __restrict__ cnt, const int* __restrict__ boffs, int Nn,
                        int* __restrict__ rowptr, int* __restrict__ cursor,
                        float4* __restrict__ nd){
  __shared__ int red[256];
  int b = blockIdx.x, t = threadIdx.x;
  int base = b*1024 + t*4;
  int c[4]; int s = 0;
  #pragma unroll
  for (int k = 0; k < 4; k++){ int i = base + k; c[k] = (i < Nn) ? cnt[i] : 0; s += c[k]; }
  red[t] = s; __syncthreads();
  for (int off = 1; off < 256; off <<= 1){
    int add = (t >= off) ? red[t - off] : 0;
    __syncthreads();
    red[t] += add;
    __syncthreads();
  }
  int run = red[t] - s + boffs[b];
  #pragma unroll
  for (int k = 0; k < 4; k++){
    int i = base + k;
    if (i < Nn){
      rowptr[i] = run; cursor[i] = run;
      float f = (float)c[k];
      nd[i].z = c[k] > 0 ? 1.f/sqrtf(f) : 0.f;   // dis
      nd[i].w = 1.f/fmaxf(f, 1.f);               // dinv
      run += c[k];
    }
  }
}

// per-node cursors: 50k addresses -> ~16 avg collisions (low contention).
// NOTE (R9 post-mortem): 128-node bucketing concentrated 800k atomics on 391
// addresses -> 281 us of atomic serialization. Do not re-bucket.
__global__ void k_fill(const int* __restrict__ ei, int E,
                       int* __restrict__ cursor, int* __restrict__ csr){
  int e = blockIdx.x*256 + threadIdx.x;
  if (e < E){
    int sv = ei[e], dv = ei[E + e];
    int pos = atomicAdd(&cursor[dv], 1);
    csr[pos] = sv;
  }
}

// ------- aggregation: wave/dst, single pass (global softmax bound) ----------
__global__ __launch_bounds__(256)
void k_agg(const u16* __restrict__ X, const int* __restrict__ rowptr, const int* __restrict__ csr,
           const float4* __restrict__ nd, const float* __restrict__ sm,
           const u32* __restrict__ maxs, int layer, int Nn,
           u16* __restrict__ Qb, u16* __restrict__ Pm, u16* __restrict__ Gb, u16* __restrict__ Rb,
           float* __restrict__ b0)
{
  int wv = blockIdx.x*4 + (threadIdx.x >> 6);
  if (wv >= Nn) return;
  int lane = threadIdx.x & 63;
  int g = lane >> 4, t = lane & 15;
  int beg = rowptr[wv], end = rowptr[wv+1];
  float4 ndw = nd[wv];
  float dval = ndw.y;
  float bnd = fdec(maxs[layer]) + dval;
  float mloc = fmaxf(bnd, 0.2f*bnd);
  f32x2 p2[4], q2[4], r2[4];
  #pragma unroll
  for (int k = 0; k < 4; k++){ p2[k] = (f32x2){0.f,0.f}; q2[k] = (f32x2){0.f,0.f}; r2[k] = (f32x2){0.f,0.f}; }
  float z = 0.f, qd = 0.f;
  int e = beg + g;
  for (; e + 4 < end; e += 8){
    int sv0 = csr[e], sv1 = csr[e+4];
    float4 n0 = nd[sv0], n1 = nd[sv1];
    uint4 xv0 = *(const uint4*)(X + (size_t)sv0*HD + (t ^ (sv0 & 15))*8);
    uint4 xv1 = *(const uint4*)(X + (size_t)sv1*HD + (t ^ (sv1 & 15))*8);
    float s0 = n0.x + dval, s1 = n1.x + dval;
    float lg0 = fmaxf(s0, 0.2f*s0);
    float lg1 = fmaxf(s1, 0.2f*s1);
    float ew0 = __expf(lg0 - mloc), ew1 = __expf(lg1 - mloc);
    u32 a0[4] = {xv0.x, xv0.y, xv0.z, xv0.w};
    u32 a1[4] = {xv1.x, xv1.y, xv1.z, xv1.w};
    f32x2 d0 = {n0.z, n0.z}, d1 = {n1.z, n1.z};
    f32x2 e0 = {ew0, ew0},   e1v = {ew1, ew1};
    #pragma unroll
    for (int k = 0; k < 4; k++){
      f32x2 xf0 = {lo2f(a0[k]), hi2f(a0[k])};
      f32x2 xf1 = {lo2f(a1[k]), hi2f(a1[k])};
      p2[k] += xf0 + xf1;
      q2[k] = __builtin_elementwise_fma(xf0, d0, q2[k]);
      q2[k] = __builtin_elementwise_fma(xf1, d1, q2[k]);
      r2[k] = __builtin_elementwise_fma(xf0, e0, r2[k]);
      r2[k] = __builtin_elementwise_fma(xf1, e1v, r2[k]);
    }
    z += ew0 + ew1; qd += n0.z + n1.z;
  }
  if (e < end){
    int sv = csr[e];
    float4 n0 = nd[sv];
    uint4 xv = *(const uint4*)(X + (size_t)sv*HD + (t ^ (sv & 15))*8);
    float s = n0.x + dval;
    float lg = fmaxf(s, 0.2f*s);
    float ew = __expf(lg - mloc);
    u32 a0[4] = {xv.x, xv.y, xv.z, xv.w};
    f32x2 d0 = {n0.z, n0.z}, e0 = {ew, ew};
    #pragma unroll
    for (int k = 0; k < 4; k++){
      f32x2 xf = {lo2f(a0[k]), hi2f(a0[k])};
      p2[k] += xf;
      q2[k] = __builtin_elementwise_fma(xf, d0, q2[k]);
      r2[k] = __builtin_elementwise_fma(xf, e0, r2[k]);
    }
    z += ew; qd += n0.z;
  }
  #pragma unroll
  for (int off = 16; off <= 32; off <<= 1){
    #pragma unroll
    for (int k = 0; k < 4; k++){
      p2[k].x += __shfl_xor(p2[k].x, off); p2[k].y += __shfl_xor(p2[k].y, off);
      q2[k].x += __shfl_xor(q2[k].x, off); q2[k].y += __shfl_xor(q2[k].y, off);
      r2[k].x += __shfl_xor(r2[k].x, off); r2[k].y += __shfl_xor(r2[k].y, off);
    }
    z  += __shfl_xor(z, off);
    qd += __shfl_xor(qd, off);
  }
  if (g == 0){
    float disv = ndw.z, dinvv = ndw.w;
    float zinv = 1.f/(z + 1e-16f);
    float e1 = sm[17 + layer];
    int tch = t ^ (wv & 15);
    size_t o = (size_t)wv*HD + tch*8;
    uint4 xo = *(const uint4*)(X + o);
    u32 ax[4] = {xo.x, xo.y, xo.z, xo.w};
    uint4 qo, po, go, ro;
    u32* qp = (u32*)&qo; u32* pp = (u32*)&po; u32* gp = (u32*)&go; u32* rp = (u32*)&ro;
    #pragma unroll
    for (int k = 0; k < 4; k++){
      float x0 = lo2f(ax[k]), x1 = hi2f(ax[k]);
      qp[k] = pack2(disv*q2[k].x, disv*q2[k].y);
      pp[k] = pack2(dinvv*p2[k].x, dinvv*p2[k].y);
      gp[k] = pack2(fmaf(e1, x0, p2[k].x), fmaf(e1, x1, p2[k].y));
      rp[k] = pack2(zinv*r2[k].x, zinv*r2[k].y);
    }
    *(uint4*)(Qb + o) = qo;
    *(uint4*)(Pm + o) = po;
    *(uint4*)(Gb + o) = go;
    *(uint4*)(Rb + o) = ro;
    if (t == 0) b0[wv] = disv*qd;
  }
}

// ---------------- MFMA helpers, M=64 tile ----------------
__device__ __forceinline__ void stageB_async(u16* lds, const u16* __restrict__ w, int tid){
  int lane = tid & 63, wave = tid >> 6;
  #pragma unroll
  for (int i = 0; i < 8; i++){
    int cb = wave*64 + 256*i;
    async16(w + (size_t)(cb + lane)*8, lds + (size_t)cb*8);
  }
}
__device__ __forceinline__ void stageA64_async(u16* lds, const u16* __restrict__ src,
                                               int mbase, int Nn, int tid){
  int lane = tid & 63, wave = tid >> 6;
  #pragma unroll
  for (int i = 0; i < 4; i++){
    int cb = wave*64 + 256*i;
    int gr = mbase + ((cb + lane) >> 4);
    if (gr < Nn)
      async16(src + ((size_t)mbase*16 + cb + lane)*8, lds + (size_t)cb*8);
  }
}
__device__ __forceinline__ void stageA64_f32(u16* lds, const float* __restrict__ src,
                                             int mbase, int Nn, int tid){
  #pragma unroll
  for (int i = 0; i < 4; i++){
    int chunk = tid + 256*i;
    int r = chunk >> 4;
    int c = chunk & 15;
    uint4 v = {0u,0u,0u,0u};
    int gr = mbase + r;
    if (gr < Nn) v = cvt8(src + (size_t)gr*HD + c*8);
    *(uint4*)(lds + (r*16 + (c ^ (r & 15)))*8) = v;
  }
}
__device__ __forceinline__ void mfma_tile64(const u16* Als, const u16* Bls,
                                            int m0, int lane, f32x4 acc[8]){
  int quad = lane >> 4, lr = lane & 15;
  #pragma unroll
  for (int ks = 0; ks < 4; ks++){
    int q = ks*4 + quad;
    short8 a, b[8];
    int row = m0 + lr;
    a = *(const short8*)(Als + (row*16 + (q ^ lr))*8);
    #pragma unroll
    for (int ct = 0; ct < 8; ct++){
      int brow = ct*16 + lr;
      b[ct] = *(const short8*)(Bls + (brow*16 + (q ^ lr))*8);
    }
    #pragma unroll
    for (int ct = 0; ct < 8; ct++)
      acc[ct] = __builtin_amdgcn_mfma_f32_16x16x32_bf16(a, b[ct], acc[ct], 0, 0, 0);
  }
}

// ---------------- lin1: xh(bf16,swz) = f32(x) @ W^T + b ----------------
__global__ __launch_bounds__(256,3)
void k_gemm1(const float* __restrict__ A, const u16* __restrict__ Wb, const float* __restrict__ bias,
             const float* __restrict__ sm, float4* __restrict__ nd, u32* __restrict__ maxs,
             int Nn, u16* __restrict__ out)
{
  __shared__ __align__(16) u16 Als[64*128];
  __shared__ __align__(16) u16 Bls[128*128];
  __shared__ float mred[4];
  int tid = threadIdx.x;
  int lane = tid & 63, wave = tid >> 6;
  int m0 = wave*16, mbase = blockIdx.x*64;
  int quad = lane >> 4, lr = lane & 15;
  f32x4 acc[8];
  #pragma unroll
  for (int ct=0;ct<8;ct++) acc[ct] = (f32x4){0.f,0.f,0.f,0.f};
  stageB_async(Bls, Wb, tid);
  stageA64_f32(Als, A, mbase, Nn, tid);
  __syncthreads();
  mfma_tile64(Als, Bls, m0, lane, acc);
  #pragma unroll
  for (int ct=0;ct<8;ct++){
    float bc = bias[ct*16+lr];
    #pragma unroll
    for (int r=0;r<4;r++) acc[ct][r] = sane(acc[ct][r] + bc);
  }
  #pragma unroll
  for (int ct=0;ct<8;ct++){
    int c2 = ct*2 + (lr >> 3);
    #pragma unroll
    for (int r=0;r<4;r++){
      int grow = mbase + m0 + quad*4 + r;
      if (grow < Nn) out[(size_t)grow*HD + (c2 ^ (grow & 15))*8 + (lr & 7)] = f2b(acc[ct][r]);
    }
  }
  {
    const float* wsv = sm + 32;
    const float* wdv = sm + 416;
    float sp[4] = {0.f,0.f,0.f,0.f}, dp[4] = {0.f,0.f,0.f,0.f};
    #pragma unroll
    for (int ct=0;ct<8;ct++){
      float wsc = wsv[ct*16+lr], wdc = wdv[ct*16+lr];
      #pragma unroll
      for (int r=0;r<4;r++){
        sp[r] = fmaf(acc[ct][r], wsc, sp[r]);
        dp[r] = fmaf(acc[ct][r], wdc, dp[r]);
      }
    }
    #pragma unroll
    for (int off=1; off<16; off<<=1)
      #pragma unroll
      for (int r=0;r<4;r++){ sp[r] += __shfl_xor(sp[r], off); dp[r] += __shfl_xor(dp[r], off); }
    float ms = -3.4e38f;
    #pragma unroll
    for (int r=0;r<4;r++){
      int grow = mbase + m0 + quad*4 + r;
      if (grow < Nn){
        ms = fmaxf(ms, sp[r]);
        if (lr == 0) *(float2*)&nd[grow] = make_float2(sp[r], dp[r]);
      }
    }
    ms = fmaxf(ms, __shfl_xor(ms, 16));
    ms = fmaxf(ms, __shfl_xor(ms, 32));
    if (lane == 0) mred[wave] = ms;
    __syncthreads();
    if (tid == 0){
      float m = fmaxf(fmaxf(mred[0],mred[1]), fmaxf(mred[2],mred[3]));
      atomicMax(maxs + 0, fenc(m));
    }
  }
}

// ---------------- fused layer: 5 all-async GEMMs + elu mix + s/d epilogue ---
__global__ __launch_bounds__(256,3)
void k_layer3(const u16* __restrict__ X, const u16* __restrict__ Qb,
              const u16* __restrict__ Pm, const u16* __restrict__ Gb, const u16* __restrict__ Rb,
              float4* __restrict__ nd, const float* __restrict__ b0,
              const u16* __restrict__ wsb,
              const float* __restrict__ gcnB, const float* __restrict__ ginB,
              const float* __restrict__ sm, u32* __restrict__ maxs,
              int layer, int Nn, u16* __restrict__ out)
{
  __shared__ __align__(16) u16 At[64*128];
  __shared__ __align__(16) u16 Bt[128*128];
  __shared__ float mred[4];
  int tid = threadIdx.x;
  int lane = tid & 63, wave = tid >> 6;
  int m0 = wave*16, mbase = blockIdx.x*64;
  int quad = lane >> 4, lr = lane & 15;
  float w0 = sm[layer*4+0], w1 = sm[layer*4+1], w2 = sm[layer*4+2], w3 = sm[layer*4+3];
  const u16* gcnWb = wsb + (size_t)(1  + layer)*16384;
  const u16* WsWb  = wsb + (size_t)(4  + layer)*16384;
  const u16* WnWb  = wsb + (size_t)(7  + layer)*16384;
  const u16* ginWb = wsb + (size_t)(10 + layer)*16384;
  const u16* gatWb = wsb + (size_t)(13 + layer)*16384;

  f32x4 mix[8];
  f32x4 acc[8];
  float b0r[4];
  #pragma unroll
  for (int r=0;r<4;r++){
    int grow = mbase + m0 + quad*4 + r;
    b0r[r] = (grow < Nn) ? b0[grow] : 0.f;
  }

  // ---- op0: GCN ----
  stageB_async(Bt, gcnWb, tid);
  stageA64_async(At, Qb, mbase, Nn, tid);
  __syncthreads();
  #pragma unroll
  for (int ct=0;ct<8;ct++) acc[ct] = (f32x4){0.f,0.f,0.f,0.f};
  mfma_tile64(At, Bt, m0, lane, acc);
  {
    float gb[8];
    #pragma unroll
    for (int ct=0;ct<8;ct++) gb[ct] = gcnB[layer*HD + ct*16+lr];
    #pragma unroll
    for (int ct=0;ct<8;ct++)
      #pragma unroll
      for (int r=0;r<4;r++)
        mix[ct][r] = w0 * eluf(acc[ct][r] + b0r[r]*gb[ct]);
  }
  __syncthreads();

  // ---- op1: SAGE self ----
  stageB_async(Bt, WsWb, tid);
  stageA64_async(At, X, mbase, Nn, tid);
  __syncthreads();
  #pragma unroll
  for (int ct=0;ct<8;ct++) acc[ct] = (f32x4){0.f,0.f,0.f,0.f};
  mfma_tile64(At, Bt, m0, lane, acc);
  __syncthreads();
  // ---- SAGE neighbor ----
  stageB_async(Bt, WnWb, tid);
  stageA64_async(At, Pm, mbase, Nn, tid);
  __syncthreads();
  mfma_tile64(At, Bt, m0, lane, acc);
  #pragma unroll
  for (int ct=0;ct<8;ct++)
    #pragma unroll
    for (int r=0;r<4;r++)
      mix[ct][r] += w1 * eluf(acc[ct][r]);
  __syncthreads();

  // ---- op2: GIN ----
  stageB_async(Bt, ginWb, tid);
  stageA64_async(At, Gb, mbase, Nn, tid);
  __syncthreads();
  #pragma unroll
  for (int ct=0;ct<8;ct++) acc[ct] = (f32x4){0.f,0.f,0.f,0.f};
  mfma_tile64(At, Bt, m0, lane, acc);
  {
    float gib[8];
    #pragma unroll
    for (int ct=0;ct<8;ct++) gib[ct] = ginB[layer*HD + ct*16+lr];
    #pragma unroll
    for (int ct=0;ct<8;ct++)
      #pragma unroll
      for (int r=0;r<4;r++)
        mix[ct][r] += w2 * eluf(acc[ct][r] + gib[ct]);
  }
  __syncthreads();

  // ---- op3: GAT ----
  stageB_async(Bt, gatWb, tid);
  stageA64_async(At, Rb, mbase, Nn, tid);
  __syncthreads();
  #pragma unroll
  for (int ct=0;ct<8;ct++) acc[ct] = (f32x4){0.f,0.f,0.f,0.f};
  mfma_tile64(At, Bt, m0, lane, acc);
  #pragma unroll
  for (int ct=0;ct<8;ct++)
    #pragma unroll
    for (int r=0;r<4;r++)
      mix[ct][r] = sane(mix[ct][r] + w3 * eluf(acc[ct][r]));

  // ---- store swizzled ----
  #pragma unroll
  for (int ct=0;ct<8;ct++){
    int c2 = ct*2 + (lr >> 3);
    #pragma unroll
    for (int r=0;r<4;r++){
      int grow = mbase + m0 + quad*4 + r;
      if (grow < Nn) out[(size_t)grow*HD + (c2 ^ (grow & 15))*8 + (lr & 7)] = f2b(mix[ct][r]);
    }
  }
  // ---- epilogue: s,d for next layer + global maxS ----
  if (layer < 2){
    const float* wsv = sm + 32  + (layer+1)*128;
    const float* wdv = sm + 416 + (layer+1)*128;
    float sp[4] = {0.f,0.f,0.f,0.f}, dp[4] = {0.f,0.f,0.f,0.f};
    #pragma unroll
    for (int ct=0;ct<8;ct++){
      float wsc = wsv[ct*16+lr], wdc = wdv[ct*16+lr];
      #pragma unroll
      for (int r=0;r<4;r++){
        sp[r] = fmaf(mix[ct][r], wsc, sp[r]);
        dp[r] = fmaf(mix[ct][r], wdc, dp[r]);
      }
    }
    #pragma unroll
    for (int off=1; off<16; off<<=1)
      #pragma unroll
      for (int r=0;r<4;r++){ sp[r] += __shfl_xor(sp[r], off); dp[r] += __shfl_xor(dp[r], off); }
    float ms = -3.4e38f;
    #pragma unroll
    for (int r=0;r<4;r++){
      int grow = mbase + m0 + quad*4 + r;
      if (grow < Nn){
        ms = fmaxf(ms, sp[r]);
        if (lr == 0) *(float2*)&nd[grow] = make_float2(sp[r], dp[r]);
      }
    }
    ms = fmaxf(ms, __shfl_xor(ms, 16));
    ms = fmaxf(ms, __shfl_xor(ms, 32));
    if (lane == 0) mred[wave] = ms;
    __syncthreads();
    if (tid == 0){
      float m = fmaxf(fmaxf(mred[0],mred[1]), fmaxf(mred[2],mred[3]));
      atomicMax(maxs + layer + 1, fenc(m));
    }
  }
}

// ------- classifier with fused skip/layer-agg (inputs swizzled) ----------
__global__ __launch_bounds__(256)
void k_nc(const u16* __restrict__ X1, const u16* __restrict__ X2, const u16* __restrict__ X3,
          const float* __restrict__ W, const float* __restrict__ bias,
          const float* __restrict__ sm, int Nn, float* __restrict__ out)
{
  __shared__ __align__(16) u16 xs[32*136];
  __shared__ __align__(16) float wn[40*132];
  __shared__ float bs[40];
  int t = threadIdx.x;
  int nb = blockIdx.x*32;
  float c1 = sm[12], c2 = sm[13], la0 = sm[14], la1 = sm[15], la2 = sm[16];
  #pragma unroll
  for (int i = 0; i < 2; i++){
    int chunk = t + 256*i;
    int r = chunk >> 4, c = chunk & 15;
    uint4 v = {0u,0u,0u,0u};
    int gr = nb + r;
    if (gr < Nn){
      size_t o = (size_t)gr*HD + ((c ^ (gr & 15))*8);
      uint4 u1 = *(const uint4*)(X1 + o);
      uint4 u2 = *(const uint4*)(X2 + o);
      uint4 u3 = *(const uint4*)(X3 + o);
      u32* u1p = (u32*)&u1; u32* u2p = (u32*)&u2; u32* u3p = (u32*)&u3; u32* vp = (u32*)&v;
      #pragma unroll
      for (int k = 0; k < 4; k++){
        float o0, o1;
        {
          float a1 = lo2f(u1p[k]), a2 = lo2f(u2p[k]), a3 = lo2f(u3p[k]);
          float t0 = a3, t1 = c1*a1, t2 = c2*a2;
          float smm = t0 + t1 + t2;
          float mx = fmaxf(fmaxf(t0,t1),t2);
          o0 = la0*reluf(mx) + la1*reluf(smm*(1.f/3.f)) + la2*reluf(smm);
        }
        {
          float a1 = hi2f(u1p[k]), a2 = hi2f(u2p[k]), a3 = hi2f(u3p[k]);
          float t0 = a3, t1 = c1*a1, t2 = c2*a2;
          float smm = t0 + t1 + t2;
          float mx = fmaxf(fmaxf(t0,t1),t2);
          o1 = la0*reluf(mx) + la1*reluf(smm*(1.f/3.f)) + la2*reluf(smm);
        }
        vp[k] = pack2(sane(o0), sane(o1));
      }
    }
    *(uint4*)(xs + r*136 + c*8) = v;
  }
  #pragma unroll
  for (int i = 0; i < 5; i++){
    int chunk = t + 256*i;
    int r = chunk >> 5, c = chunk & 31;
    *(float4*)(wn + r*132 + c*4) = *(const float4*)(W + r*HD + c*4);
  }
  if (t < 40) bs[t] = bias[t];
  __syncthreads();
  int nl = t >> 3, cg = t & 7;
  float acc[5];
  #pragma unroll
  for (int j = 0; j < 5; j++) acc[j] = bs[cg + 8*j];
  for (int k = 0; k < 128; k++){
    float xv = b2f(xs[nl*136 + k]);
    #pragma unroll
    for (int j = 0; j < 5; j++)
      acc[j] = fmaf(xv, wn[(cg + 8*j)*132 + k], acc[j]);
  }
  int gr = nb + nl;
  if (gr < Nn){
    #pragma unroll
    for (int j = 0; j < 5; j++)
      out[(size_t)gr*40 + cg + 8*j] = sane(acc[j]);
  }
}

// ---------------- host ----------------
extern "C" void kernel_launch(void* const* d_in, const int* in_sizes, int n_in,
                              void* d_out, int out_size, void* d_ws, size_t ws_size,
                              hipStream_t stream)
{
  (void)n_in; (void)out_size; (void)ws_size;
  const int N = in_sizes[0] / HD;
  const int E = in_sizes[1] / 2;
  const float* x      = (const float*)d_in[0];
  const int*   ei     = (const int*)d_in[1];
  const float* na_a   = (const float*)d_in[2];
  const float* sc_a   = (const float*)d_in[3];
  const float* la_a   = (const float*)d_in[4];
  const float* lin1W  = (const float*)d_in[5];
  const float* lin1b  = (const float*)d_in[6];
  const float* gcnW   = (const float*)d_in[7];
  const float* gcnB   = (const float*)d_in[8];
  const float* sageWs = (const float*)d_in[9];
  const float* sageWn = (const float*)d_in[10];
  const float* ginW   = (const float*)d_in[11];
  const float* ginB   = (const float*)d_in[12];
  const float* ginE   = (const float*)d_in[13];
  const float* gatW   = (const float*)d_in[14];
  const float* gatAs  = (const float*)d_in[15];
  const float* gatAd  = (const float*)d_in[16];
  const float* ncW    = (const float*)d_in[17];
  const float* ncB    = (const float*)d_in[18];

  char* base = (char*)d_ws;
  size_t off = 0;
  auto alloc = [&](size_t b) -> void* {
    void* p = base + off;
    off += (b + 255) & ~(size_t)255;
    return p;
  };
  const int NB = (N + 1023) / 1024;
  float*  smalls = (float*)alloc(4096);
  u32*    maxs   = (u32*)alloc(256);
  int*    cnt    = (int*)alloc((size_t)N*4);
  int*    rowptr = (int*)alloc(((size_t)N+1)*4);
  int*    cursor = (int*)alloc((size_t)N*4);
  int*    bsum   = (int*)alloc(4096);
  int*    boffs  = (int*)alloc(4096);
  float4* nd     = (float4*)alloc((size_t)N*16);
  float*  b0     = (float*)alloc((size_t)N*4);
  int*    csr    = (int*)alloc((size_t)E*4);
  u16*    wsb    = (u16*)alloc((size_t)16*16384*2);
  u16*    xh     = (u16*)alloc((size_t)N*HD*2);
  u16*    x1     = (u16*)alloc((size_t)N*HD*2);
  u16*    x2     = (u16*)alloc((size_t)N*HD*2);
  u16*    Qb     = (u16*)alloc((size_t)N*HD*2);
  u16*    Pm     = (u16*)alloc((size_t)N*HD*2);
  u16*    Gb     = (u16*)alloc((size_t)N*HD*2);
  u16*    Rb     = (u16*)alloc((size_t)N*HD*2);

  hipMemsetAsync(cnt, 0, (size_t)N*4, stream);
  k_small<<<1,128,0,stream>>>(na_a, sc_a, la_a, gatW, gatAs, gatAd, ginE, smalls, maxs);
  k_wcvt<<<128,256,0,stream>>>(lin1W, gcnW, sageWs, sageWn, ginW, gatW, wsb);
  int ebl = (E + 255)/256;
  k_count<<<ebl,256,0,stream>>>(ei, E, cnt);
  k_scan1<<<NB,256,0,stream>>>(cnt, N, bsum);
  k_scan2<<<1,1024,0,stream>>>(bsum, NB, boffs, rowptr, N);
  k_scan3<<<NB,256,0,stream>>>(cnt, boffs, N, rowptr, cursor, nd);
  k_fill<<<ebl,256,0,stream>>>(ei, E, cursor, csr);
  int gbl64 = (N + 63)/64;
  k_gemm1<<<gbl64,256,0,stream>>>(x, wsb, lin1b, smalls, nd, maxs, N, xh);
  const u16* xc = xh;
  u16* outs[3] = {x1, x2, xh};
  int wbl = (N + 3)/4;
  for (int l = 0; l < 3; l++){
    k_agg<<<wbl,256,0,stream>>>(xc, rowptr, csr, nd, smalls, maxs, l, N, Qb, Pm, Gb, Rb, b0);
    k_layer3<<<gbl64,256,0,stream>>>(xc, Qb, Pm, Gb, Rb, nd, b0, wsb,
                                     gcnB, ginB, smalls, maxs, l, N, outs[l]);
    xc = outs[l];
  }
  int ncbl = (N + 31)/32;
  k_nc<<<ncbl,256,0,stream>>>(x1, x2, xh, ncW, ncB, smalls, N, (float*)d_out);
}